// Round 7
// baseline (817.066 us; speedup 1.0000x reference)
//
#include <hip/hip_runtime.h>
#include <hip/hip_fp16.h>

#define B_ 64
#define L_ 2048
#define D_ 256
#define TC 16
#define TP 32

typedef _Float16 half8 __attribute__((ext_vector_type(8)));
typedef _Float16 f16x2 __attribute__((ext_vector_type(2)));
typedef float f32x4 __attribute__((ext_vector_type(4)));

#define LOG2E 1.4426950408889634f
#define TWO_LOG2E 2.8853900817779268f

__device__ __forceinline__ float ex2(float x){ return __builtin_amdgcn_exp2f(x); }
__device__ __forceinline__ float rcp_(float x){ return __builtin_amdgcn_rcpf(x); }
__device__ __forceinline__ float sigm(float x){ return rcp_(1.f + ex2(-LOG2E*x)); }
__device__ __forceinline__ float tanh_(float x){ return 1.f - 2.f*rcp_(1.f + ex2(TWO_LOG2E*x)); }

#if __has_builtin(__builtin_amdgcn_fdot2)
__device__ __forceinline__ float fdot2_(f16x2 a, f16x2 b, float c){ return __builtin_amdgcn_fdot2(a,b,c,false); }
#else
__device__ __forceinline__ float fdot2_(f16x2 a, f16x2 b, float c){
  return fmaf((float)a[0], (float)b[0], fmaf((float)a[1], (float)b[1], c));
}
#endif

__device__ __forceinline__ void cvt8(uint4 v, float* w){
  const __half2* h = (const __half2*)&v;
#pragma unroll
  for (int i=0;i<4;i++){ float2 f = __half22float2(h[i]); w[2*i]=f.x; w[2*i+1]=f.y; }
}

// ---------------- K1: weight prep (fp16 casts, transposed Wk, parentT) ----------------
__global__ __launch_bounds__(256) void k_prep(
    const float* __restrict__ sf,
    const float* __restrict__ wk_c, const float* __restrict__ wk_p,
    const float* __restrict__ wih_c, const float* __restrict__ wih_p,
    const float* __restrict__ whh_c, const float* __restrict__ whh_p,
    __half* __restrict__ wkT, __half* __restrict__ wihH, __half* __restrict__ whhH,
    float* __restrict__ parentT)
{
  int idx = blockIdx.x*256 + threadIdx.x;
  if (idx < 131072) {
    int c = idx >> 8, d = idx & 255;
    int net = c >> 8, e = c & 255;
    const float* w = net ? wk_p : wk_c;
    wkT[idx] = __float2half(w[d*256 + e]);           // wkT[c][d] = Wk[d][e]
  } else if (idx < 131072 + 393216) {
    int i = idx - 131072;
    const float* w = (i < 196608) ? wih_c : wih_p;
    wihH[i] = __float2half(w[(i < 196608) ? i : i - 196608]);
  } else if (idx < 131072 + 786432) {
    int i = idx - 131072 - 393216;
    const float* w = (i < 196608) ? whh_c : whh_p;
    whhH[i] = __float2half(w[(i < 196608) ? i : i - 196608]);
  } else {
    int i = idx - 131072 - 786432;                   // < 16384
    int d = i >> 6, b = i & 63;
    parentT[i] = sf[((size_t)b*L_ + (L_-2))*D_ + d];
  }
}

// ---------------- K2: proj_k GEMM -> E[r][c] = exp(2*pk) as clamped fp16 --------------
// XCD-aware swizzle (proven R3): each XCD owns a contiguous band of row-blocks; the 4
// col-siblings of a row-block sit in consecutive within-XCD slots -> sf read once/XCD.
// Launched LAST before the fused consumers so E stays L3-warm.
__global__ __launch_bounds__(256) void k_gemm(
    const float* __restrict__ sf, const __half* __restrict__ wkT, __half* __restrict__ Eo)
{
  __shared__ __half As[128*40];
  __shared__ __half Bs[128*40];
  const int tid = threadIdx.x;
  const int bid = blockIdx.x;
  const int xcd = bid & 7;
  const int w_  = bid >> 3;                 // 0..511
  const int row0 = (xcd*128 + (w_ >> 2)) * 128;
  const int col0 = (w_ & 3) * 128;
  const int lane = tid & 63, wave = tid >> 6;
  const int wm = wave & 1, wn = wave >> 1;
  const int qd = lane >> 4, mr = lane & 15;
  const int rl = tid >> 1, hf = tid & 1;

  f32x4 acc[4][4];
#pragma unroll
  for (int i=0;i<4;i++)
#pragma unroll
    for (int j=0;j<4;j++) acc[i][j] = (f32x4){0.f,0.f,0.f,0.f};

  for (int kc = 0; kc < 256; kc += 32) {
    const float* asrc = sf + ((size_t)(row0+rl))*256 + kc + hf*16;
    __half* adst = As + rl*40 + hf*16;
#pragma unroll
    for (int i=0;i<4;i++){
      float4 v = ((const float4*)asrc)[i];
      __half2 h01 = __floats2half2_rn(v.x, v.y);
      __half2 h23 = __floats2half2_rn(v.z, v.w);
      uint2 u; u.x = *(const unsigned*)&h01; u.y = *(const unsigned*)&h23;
      *(uint2*)(adst + i*4) = u;
    }
    const __half* bsrc = wkT + (size_t)(col0+rl)*256 + kc + hf*16;
    __half* bdst = Bs + rl*40 + hf*16;
    *(uint4*)bdst       = *(const uint4*)bsrc;
    *(uint4*)(bdst + 8) = *(const uint4*)(bsrc + 8);
    __syncthreads();

    half8 af[4], bf[4];
#pragma unroll
    for (int tm=0;tm<4;tm++) af[tm] = *(const half8*)(As + (wm*64 + tm*16 + mr)*40 + qd*8);
#pragma unroll
    for (int tn=0;tn<4;tn++) bf[tn] = *(const half8*)(Bs + (wn*64 + tn*16 + mr)*40 + qd*8);
#pragma unroll
    for (int tm=0;tm<4;tm++)
#pragma unroll
      for (int tn=0;tn<4;tn++)
        acc[tm][tn] = __builtin_amdgcn_mfma_f32_16x16x32_f16(af[tm], bf[tn], acc[tm][tn], 0,0,0);
    __syncthreads();
  }
#pragma unroll
  for (int tm=0;tm<4;tm++)
#pragma unroll
    for (int tn=0;tn<4;tn++){
      int c = col0 + wn*64 + tn*16 + mr;
#pragma unroll
      for (int rg=0; rg<4; rg++){
        int r = row0 + wm*64 + tm*16 + qd*4 + rg;
        float e = ex2(TWO_LOG2E * acc[tm][tn][rg]);       // e^{2*pk}
        Eo[(size_t)r*512 + c] = __float2half(fminf(e, 65000.f));
      }
    }
}

// ---------------- K3: M[net][b][k][e] = sum_d parent[b][d]*bilW[k][d][e]  (fp32) ------
__global__ __launch_bounds__(256) void k_M(
    const float* __restrict__ bw_c, const float* __restrict__ bw_p,
    const float* __restrict__ parentT, float* __restrict__ M)
{
  const int net = blockIdx.x >> 8;
  const int k = blockIdx.x & 255;
  const int e = threadIdx.x;
  __shared__ float pl[16384];           // [d][b], 64 KB
#pragma unroll
  for (int r=0;r<16;r++){
    int f4 = r*256 + threadIdx.x;       // 0..4095
    ((float4*)pl)[f4] = ((const float4*)parentT)[f4];
  }
  __syncthreads();

  const float* W = (net ? bw_p : bw_c) + (size_t)k*65536 + e;
  float acc[64];
#pragma unroll
  for (int b=0;b<64;b++) acc[b] = 0.f;
  float wcur = W[0];
  for (int d=0; d<256; d++){
    float wnext = (d < 255) ? W[(size_t)(d+1)*256] : 0.f;
    const float4* pr = (const float4*)(pl + d*64);
#pragma unroll
    for (int c=0;c<16;c++){
      float4 pv = pr[c];
      acc[c*4+0] = fmaf(pv.x, wcur, acc[c*4+0]);
      acc[c*4+1] = fmaf(pv.y, wcur, acc[c*4+1]);
      acc[c*4+2] = fmaf(pv.z, wcur, acc[c*4+2]);
      acc[c*4+3] = fmaf(pv.w, wcur, acc[c*4+3]);
    }
    wcur = wnext;
  }
  float* Mo = M + ((size_t)net*64*256 + k)*256 + e;
#pragma unroll
  for (int b=0;b<64;b++) Mo[(size_t)b*65536] = acc[b];
}

// ---------------- K4a: gi_all[b][t][j] = x_t[b] . Wih[j] + bih[j] (all t parallel) ----
template<int T>
__global__ __launch_bounds__(256) void k_gi(
    const float* __restrict__ sf, const int* __restrict__ gold,
    const __half* __restrict__ wih, const float* __restrict__ bih,
    float* __restrict__ gi_all)
{
  const int jc = blockIdx.x % 3;
  const int bb = blockIdx.x / 3;
  __shared__ float xs[T-1][256];
  const int* gr = gold + bb*T;
  for (int t=0; t<T-1; t++)
    xs[t][threadIdx.x] = sf[((size_t)bb*L_ + gr[t])*D_ + threadIdx.x];
  __syncthreads();
  const int j = jc*256 + threadIdx.x;
  const __half* wr = wih + (size_t)j*256;
  float acc[T-1];
#pragma unroll
  for (int t=0;t<T-1;t++) acc[t] = 0.f;
  for (int d0=0; d0<256; d0+=8){
    uint4 wv = *(const uint4*)(wr + d0);
    float w[8]; cvt8(wv, w);
#pragma unroll
    for (int t=0;t<T-1;t++){
      const float* xr = &xs[t][d0];
      float4 a = *(const float4*)xr;
      float4 b = *(const float4*)(xr+4);
      acc[t] += w[0]*a.x + w[1]*a.y + w[2]*a.z + w[3]*a.w
              + w[4]*b.x + w[5]*b.y + w[6]*b.z + w[7]*b.w;
    }
  }
  float bias = bih[j];
  float* go = gi_all + ((size_t)bb*32)*768 + j;
#pragma unroll
  for (int t=0;t<T-1;t++) go[(size_t)t*768] = acc[t] + bias;
}

// ---------------- K4b: GRU recurrence, Whh held in VGPRs (128/thread) ------------------
__global__ __launch_bounds__(768, 3) void k_gru(
    const float* __restrict__ query_c, const float* __restrict__ query_p,
    const __half* __restrict__ whhH,
    const float* __restrict__ bhh_c, const float* __restrict__ bhh_p,
    const float* __restrict__ gi_all, float* __restrict__ sibT)
{
  const int net = blockIdx.x >> 6, bb = blockIdx.x & 63;
  const int T = net ? TP : TC;
  const int j = threadIdx.x;
  __shared__ float hs[256];
  __shared__ __half hsh[256];
  __shared__ float gh[768];
  const __half* wr = whhH + (size_t)net*196608 + (size_t)j*256;
  const float bias = (net ? bhh_p : bhh_c)[j];
  const float* gir = gi_all + (size_t)(net*64+bb)*32*768;
  float* sib = sibT + (size_t)(net*64+bb)*256*32;
  const float* query = net ? query_p : query_c;

  uint4 wreg[32];
#pragma unroll
  for (int i=0;i<32;i++) wreg[i] = ((const uint4*)wr)[i];

  if (j < 256){ float h0 = query[j]; hs[j]=h0; hsh[j]=__float2half(h0); sib[j*32]=h0; }
  __syncthreads();
  for (int t=0; t<T-1; t++){
    float a0 = bias, a1 = 0.f, a2 = 0.f, a3 = 0.f;
#pragma unroll
    for (int i=0;i<32;i+=4){
      uint4 hv0 = ((const uint4*)hsh)[i+0];
      uint4 hv1 = ((const uint4*)hsh)[i+1];
      uint4 hv2 = ((const uint4*)hsh)[i+2];
      uint4 hv3 = ((const uint4*)hsh)[i+3];
      const f16x2* wp0 = (const f16x2*)&wreg[i+0]; const f16x2* hp0 = (const f16x2*)&hv0;
      const f16x2* wp1 = (const f16x2*)&wreg[i+1]; const f16x2* hp1 = (const f16x2*)&hv1;
      const f16x2* wp2 = (const f16x2*)&wreg[i+2]; const f16x2* hp2 = (const f16x2*)&hv2;
      const f16x2* wp3 = (const f16x2*)&wreg[i+3]; const f16x2* hp3 = (const f16x2*)&hv3;
#pragma unroll
      for (int i2=0;i2<4;i2++){
        a0 = fdot2_(wp0[i2], hp0[i2], a0);
        a1 = fdot2_(wp1[i2], hp1[i2], a1);
        a2 = fdot2_(wp2[i2], hp2[i2], a2);
        a3 = fdot2_(wp3[i2], hp3[i2], a3);
      }
    }
    gh[j] = (a0 + a1) + (a2 + a3);
    __syncthreads();
    if (j < 256){
      const float* gi = gir + (size_t)t*768;
      float r = sigm(gi[j] + gh[j]);
      float z = sigm(gi[256+j] + gh[256+j]);
      float n = tanh_(gi[512+j] + r*gh[512+j]);
      float hn = (1.f - z)*n + z*hs[j];
      hs[j] = hn; hsh[j] = __float2half(hn);
      sib[j*32 + t + 1] = hn;
    }
    __syncthreads();
  }
}

// ---------------- K5: fused q -> qq -> Q=exp(2*qq), per (net,b,tchunk of 8) -----------
// Q clamped at 3e4 so the fused quad products stay in fp32 range.
__global__ __launch_bounds__(256) void k_qt(
    const float* __restrict__ M, const float* __restrict__ sibT,
    const float* __restrict__ bb_c, const float* __restrict__ bb_p,
    const float* __restrict__ wq_c, const float* __restrict__ wq_p,
    const float* __restrict__ ab_c, const float* __restrict__ ab_p,
    float* __restrict__ Qo)
{
  const int bb = blockIdx.x;
  const int y = blockIdx.y;
  const int net = (y >= 2) ? 1 : 0;
  const int t0 = net ? (y-2)*8 : y*8;
  const int tid = threadIdx.x;
  __shared__ float qs[256][8];
  __shared__ float slds[256][8];

  {
    const float* sr = sibT + ((size_t)(net*64+bb))*256*32 + t0;
#pragma unroll
    for (int r=0;r<2;r++){
      int f4 = r*256 + tid;              // 0..511
      int e = f4 >> 1, hh = f4 & 1;
      *(float4*)&slds[e][hh*4] = *(const float4*)(sr + (size_t)e*32 + hh*4);
    }
  }
  __syncthreads();

  const float* Mr = M + (((size_t)(net*64+bb))*256 + tid)*256;
  float accq[8];
  const float b0 = (net ? bb_p : bb_c)[tid];
#pragma unroll
  for (int t=0;t<8;t++) accq[t] = b0;
  for (int e0=0; e0<256; e0+=4){
    float4 m4 = *(const float4*)(Mr + e0);
#pragma unroll
    for (int ee=0; ee<4; ee++){
      float4 sa = *(const float4*)&slds[e0+ee][0];
      float4 sb = *(const float4*)&slds[e0+ee][4];
      float mv = ((const float*)&m4)[ee];
      accq[0] = fmaf(mv, sa.x, accq[0]); accq[1] = fmaf(mv, sa.y, accq[1]);
      accq[2] = fmaf(mv, sa.z, accq[2]); accq[3] = fmaf(mv, sa.w, accq[3]);
      accq[4] = fmaf(mv, sb.x, accq[4]); accq[5] = fmaf(mv, sb.y, accq[5]);
      accq[6] = fmaf(mv, sb.z, accq[6]); accq[7] = fmaf(mv, sb.w, accq[7]);
    }
  }
#pragma unroll
  for (int t=0;t<8;t++) qs[tid][t] = accq[t];
  __syncthreads();

  const float* wq = (net ? wq_p : wq_c) + tid;
  float acc2[8];
  const float a0 = (net ? ab_p : ab_c)[tid];
#pragma unroll
  for (int t=0;t<8;t++) acc2[t] = a0;
  for (int k=0; k<256; k++){
    float w = wq[(size_t)k*256];
#pragma unroll
    for (int t=0;t<8;t++) acc2[t] = fmaf(qs[k][t], w, acc2[t]);
  }
  float* qo = Qo + (((size_t)(net*64+bb))*256 + tid)*32 + t0;
#pragma unroll
  for (int t=0;t<8;t++) qo[t] = fminf(ex2(TWO_LOG2E * acc2[t]), 3.0e4f);
}

// ---------------- K6: fused scores + exp + partial softmax sums ------------------------
// VISIBILITY SPLIT (R7): one dispatch per NC (claim / prem-t0 / prem-t16), 512 blocks
// each (~54us) — frees top-5 slots so the hidden middle kernels (k_gemm, k_M, ...)
// surface with counters next round. Inner loop identical to the proven R3/R6 form
// (56 VGPR). NC=2 re-reads the prem E-half; nothing runs between p1 and p2 and E fits
// L3 (134 MB < 256 MB), so the re-read is an L3 hit (~4us), not HBM.
template<int NC>
__global__ __launch_bounds__(256) void k_fusedN(
    const __half* __restrict__ E, const float* __restrict__ Q,
    const float* __restrict__ av_c, const float* __restrict__ av_p,
    const int* __restrict__ mask,
    const int* __restrict__ gold_c, const int* __restrict__ gold_p,
    float* __restrict__ partials, float* __restrict__ gold_e)
{
  const int id = blockIdx.x;               // 0..511
  const int lc = id >> 6, bb = id & 63;
  const int net = NC ? 1 : 0;
  const int t0 = (NC == 2) ? 16 : 0;
  const int l  = lc*256 + threadIdx.x;
  const __half* pr = E + ((size_t)bb*L_ + l)*512 + net*256;
  const float* qr = Q + ((size_t)(net*64+bb))*256*32 + t0;      // uniform -> s_load
  const float* av = net ? av_p : av_c;

  float acc[16];
#pragma unroll
  for (int t=0;t<16;t++) acc[t] = 0.f;

  for (int d0=0; d0<256; d0+=8){
    uint4 pv = *(const uint4*)(pr + d0);
    float x[8]; cvt8(pv, x);
#pragma unroll
    for (int h=0; h<2; h++){                         // two d-quads per 8 E values
      const int d = d0 + h*4;
      const float v0 = av[d+0], v1 = av[d+1], v2 = av[d+2], v3 = av[d+3];
      const float xa = x[h*4+0], xb = x[h*4+1], xc = x[h*4+2], xd = x[h*4+3];
      const float* q0p = qr + (size_t)(d+0)*32;
      const float* q1p = qr + (size_t)(d+1)*32;
      const float* q2p = qr + (size_t)(d+2)*32;
      const float* q3p = qr + (size_t)(d+3)*32;
#pragma unroll
      for (int tc=0; tc<16; tc+=4){
        float4 qa  = *(const float4*)(q0p + tc);
        float4 qb  = *(const float4*)(q1p + tc);
        float4 qc  = *(const float4*)(q2p + tc);
        float4 qd4 = *(const float4*)(q3p + tc);
        const float qas[4] = {qa.x, qa.y, qa.z, qa.w};
        const float qbs[4] = {qb.x, qb.y, qb.z, qb.w};
        const float qcs[4] = {qc.x, qc.y, qc.z, qc.w};
        const float qds[4] = {qd4.x,qd4.y,qd4.z,qd4.w};
#pragma unroll
        for (int tt=0; tt<4; tt++){
          float ta = fmaf(xa, qas[tt], 1.f);
          float tb = fmaf(xb, qbs[tt], 1.f);
          float tcv= fmaf(xc, qcs[tt], 1.f);
          float td = fmaf(xd, qds[tt], 1.f);
          float t01 = ta*tb, t23 = tcv*td;
          float n01 = fmaf(v0, tb, v1*ta);
          float n23 = fmaf(v2, td, v3*tcv);
          float num = fmaf(n01, t23, n23*t01);
          float den = t01*t23;
          acc[tc+tt] = fmaf(num, rcp_(den), acc[tc+tt]);
        }
      }
    }
  }

  // exp(score) = exp(-2*acc); masked -> 0 contribution (matches exp(NEG) ~ 0)
  const int m_ = mask[bb*L_ + l];
  float ex[16];
#pragma unroll
  for (int t=0;t<16;t++) ex[t] = m_ ? ex2(-TWO_LOG2E * acc[t]) : 0.f;

  // capture gold numerator (exactly one thread per (t) matches across the lc-grid)
  const int* g = net ? (gold_p + bb*TP + t0) : (gold_c + bb*TC);
#pragma unroll
  for (int t=0;t<16;t++)
    if (l == g[t]) gold_e[net*2048 + bb*32 + t0 + t] = ex[t];

  // wave reduction (64 lanes)
#pragma unroll
  for (int off=1; off<64; off<<=1)
#pragma unroll
    for (int t=0;t<16;t++) ex[t] += __shfl_xor(ex[t], off, 64);

  __shared__ float red4[4][16];
  const int lane = threadIdx.x & 63, wave = threadIdx.x >> 6;
  if (lane == 0)
#pragma unroll
    for (int t=0;t<16;t++) red4[wave][t] = ex[t];
  __syncthreads();
  if (threadIdx.x < 16){
    float s = red4[0][threadIdx.x] + red4[1][threadIdx.x]
            + red4[2][threadIdx.x] + red4[3][threadIdx.x];
    partials[(((size_t)NC*64 + bb)*8 + lc)*16 + threadIdx.x] = s;
  }
}

// ---------------- K7: finalize -> out = gold_e / sum(partials) -------------------------
__global__ __launch_bounds__(256) void k_fin(
    const float* __restrict__ partials, const float* __restrict__ gold_e,
    float* __restrict__ out)
{
  int id = blockIdx.x*256 + threadIdx.x;
  if (id >= 3072) return;
  int net, bb, t, nc, tt;
  if (id < 1024){ net=0; bb=id>>4; t=id&15; nc=0; tt=t; }
  else { int i=id-1024; net=1; bb=i>>5; t=i&31; nc=1+(t>>4); tt=t&15; }
  const float* pr = partials + (((size_t)nc*64 + bb)*8)*16 + tt;
  float s = 0.f;
#pragma unroll
  for (int lcx=0; lcx<8; lcx++) s += pr[lcx*16];
  out[net ? (1024 + bb*TP + t) : (bb*TC + t)] = gold_e[net*2048 + bb*32 + t] / s;
}

extern "C" void kernel_launch(void* const* d_in, const int* in_sizes, int n_in,
                              void* d_out, int out_size, void* d_ws, size_t ws_size,
                              hipStream_t stream)
{
  const float* sf      = (const float*)d_in[0];
  const int*   mask    = (const int*)d_in[1];
  const int*   gold_c  = (const int*)d_in[2];
  const int*   gold_p  = (const int*)d_in[3];
  const float* query_c = (const float*)d_in[4];
  const float* query_p = (const float*)d_in[5];
  const float* c_bw  = (const float*)d_in[6];
  const float* c_bb  = (const float*)d_in[7];
  const float* c_wq  = (const float*)d_in[8];
  const float* c_wk  = (const float*)d_in[9];
  const float* c_ab  = (const float*)d_in[10];
  const float* c_av  = (const float*)d_in[11];
  const float* c_wih = (const float*)d_in[12];
  const float* c_whh = (const float*)d_in[13];
  const float* c_bih = (const float*)d_in[14];
  const float* c_bhh = (const float*)d_in[15];
  const float* p_bw  = (const float*)d_in[16];
  const float* p_bb  = (const float*)d_in[17];
  const float* p_wq  = (const float*)d_in[18];
  const float* p_wk  = (const float*)d_in[19];
  const float* p_ab  = (const float*)d_in[20];
  const float* p_av  = (const float*)d_in[21];
  const float* p_wih = (const float*)d_in[22];
  const float* p_whh = (const float*)d_in[23];
  const float* p_bih = (const float*)d_in[24];
  const float* p_bhh = (const float*)d_in[25];
  float* out = (float*)d_out;

  char* w = (char*)d_ws;
  size_t o = 0;
  auto take = [&](size_t bytes){ char* p = w + o; o += (bytes + 255) & ~(size_t)255; return p; };
  __half* E      = (__half*)take((size_t)131072*512*2);       // 134.2 MB  e^{2 pk}
  float*  M      = (float*) take((size_t)2*64*256*256*4);     //  33.6 MB
  float*  Q      = (float*) take((size_t)2*64*256*32*4);      //   4.2 MB  e^{2 qq} (clamped)
  float*  sibT   = (float*) take((size_t)2*64*256*32*4);      //   4.2 MB
  float*  gi_all = (float*) take((size_t)2*64*32*768*4);      //  25.2 MB
  float*  partials=(float*) take((size_t)3*64*8*16*4);        // 196 KB
  float*  gold_e = (float*) take((size_t)2*64*32*4);          //  16 KB
  __half* wkT    = (__half*)take((size_t)512*256*2);
  __half* wihH   = (__half*)take((size_t)2*768*256*2);
  __half* whhH   = (__half*)take((size_t)2*768*256*2);
  float*  parentT= (float*) take((size_t)256*64*4);
  (void)ws_size; (void)in_sizes; (void)n_in; (void)out_size;

  // Order: everything that would pollute L3 runs BEFORE k_gemm, so E (written by
  // k_gemm) is still L3-resident when the fused consumers read it.
  k_prep<<<3648, 256, 0, stream>>>(sf, c_wk, p_wk, c_wih, p_wih, c_whh, p_whh,
                                   wkT, wihH, whhH, parentT);
  k_M<<<512, 256, 0, stream>>>(c_bw, p_bw, parentT, M);
  k_gi<TC><<<192, 256, 0, stream>>>(sf, gold_c, wihH,          c_bih, gi_all);
  k_gi<TP><<<192, 256, 0, stream>>>(sf, gold_p, wihH + 196608, p_bih, gi_all + (size_t)64*32*768);
  k_gru<<<128, 768, 0, stream>>>(query_c, query_p, whhH, c_bhh, p_bhh, gi_all, sibT);
  k_qt<<<dim3(64,6), 256, 0, stream>>>(M, sibT, c_bb, p_bb, c_wq, p_wq, c_ab, p_ab, Q);
  k_gemm<<<4096, 256, 0, stream>>>(sf, wkT, E);
  k_fusedN<0><<<512, 256, 0, stream>>>(E, Q, c_av, p_av, mask, gold_c, gold_p,
                                       partials, gold_e);
  k_fusedN<1><<<512, 256, 0, stream>>>(E, Q, c_av, p_av, mask, gold_c, gold_p,
                                       partials, gold_e);
  k_fusedN<2><<<512, 256, 0, stream>>>(E, Q, c_av, p_av, mask, gold_c, gold_p,
                                       partials, gold_e);
  k_fin<<<12, 256, 0, stream>>>(partials, gold_e, out);
}

// Round 8
// 729.066 us; speedup vs baseline: 1.1207x; 1.1207x over previous
//
#include <hip/hip_runtime.h>
#include <hip/hip_fp16.h>

#define B_ 64
#define L_ 2048
#define D_ 256
#define TC 16
#define TP 32

typedef _Float16 half8 __attribute__((ext_vector_type(8)));
typedef _Float16 f16x2 __attribute__((ext_vector_type(2)));
typedef float f32x4 __attribute__((ext_vector_type(4)));

#define LOG2E 1.4426950408889634f
#define TWO_LOG2E 2.8853900817779268f

__device__ __forceinline__ float ex2(float x){ return __builtin_amdgcn_exp2f(x); }
__device__ __forceinline__ float rcp_(float x){ return __builtin_amdgcn_rcpf(x); }
__device__ __forceinline__ float sigm(float x){ return rcp_(1.f + ex2(-LOG2E*x)); }
__device__ __forceinline__ float tanh_(float x){ return 1.f - 2.f*rcp_(1.f + ex2(TWO_LOG2E*x)); }

#if __has_builtin(__builtin_amdgcn_fdot2)
__device__ __forceinline__ float fdot2_(f16x2 a, f16x2 b, float c){ return __builtin_amdgcn_fdot2(a,b,c,false); }
#else
__device__ __forceinline__ float fdot2_(f16x2 a, f16x2 b, float c){
  return fmaf((float)a[0], (float)b[0], fmaf((float)a[1], (float)b[1], c));
}
#endif

__device__ __forceinline__ void cvt8(uint4 v, float* w){
  const __half2* h = (const __half2*)&v;
#pragma unroll
  for (int i=0;i<4;i++){ float2 f = __half22float2(h[i]); w[2*i]=f.x; w[2*i+1]=f.y; }
}

// ---------------- K1: weight prep (fp16 casts, transposed Wk, parentT) ----------------
__global__ __launch_bounds__(256) void k_prep(
    const float* __restrict__ sf,
    const float* __restrict__ wk_c, const float* __restrict__ wk_p,
    const float* __restrict__ wih_c, const float* __restrict__ wih_p,
    const float* __restrict__ whh_c, const float* __restrict__ whh_p,
    __half* __restrict__ wkT, __half* __restrict__ wihH, __half* __restrict__ whhH,
    float* __restrict__ parentT)
{
  int idx = blockIdx.x*256 + threadIdx.x;
  if (idx < 131072) {
    int c = idx >> 8, d = idx & 255;
    int net = c >> 8, e = c & 255;
    const float* w = net ? wk_p : wk_c;
    wkT[idx] = __float2half(w[d*256 + e]);           // wkT[c][d] = Wk[d][e]
  } else if (idx < 131072 + 393216) {
    int i = idx - 131072;
    const float* w = (i < 196608) ? wih_c : wih_p;
    wihH[i] = __float2half(w[(i < 196608) ? i : i - 196608]);
  } else if (idx < 131072 + 786432) {
    int i = idx - 131072 - 393216;
    const float* w = (i < 196608) ? whh_c : whh_p;
    whhH[i] = __float2half(w[(i < 196608) ? i : i - 196608]);
  } else {
    int i = idx - 131072 - 786432;                   // < 16384
    int d = i >> 6, b = i & 63;
    parentT[i] = sf[((size_t)b*L_ + (L_-2))*D_ + d];
  }
}

// ---------------- K2: proj_k GEMM -> E[r][c] = exp(2*pk) as clamped fp16 --------------
// XCD-aware swizzle (proven R3): each XCD owns a contiguous band of row-blocks; the 4
// col-siblings of a row-block sit in consecutive within-XCD slots -> sf read once/XCD.
// Launched LAST before k_fused so E stays L3-warm for the consumer.
__global__ __launch_bounds__(256) void k_gemm(
    const float* __restrict__ sf, const __half* __restrict__ wkT, __half* __restrict__ Eo)
{
  __shared__ __half As[128*40];
  __shared__ __half Bs[128*40];
  const int tid = threadIdx.x;
  const int bid = blockIdx.x;
  const int xcd = bid & 7;
  const int w_  = bid >> 3;                 // 0..511
  const int row0 = (xcd*128 + (w_ >> 2)) * 128;
  const int col0 = (w_ & 3) * 128;
  const int lane = tid & 63, wave = tid >> 6;
  const int wm = wave & 1, wn = wave >> 1;
  const int qd = lane >> 4, mr = lane & 15;
  const int rl = tid >> 1, hf = tid & 1;

  f32x4 acc[4][4];
#pragma unroll
  for (int i=0;i<4;i++)
#pragma unroll
    for (int j=0;j<4;j++) acc[i][j] = (f32x4){0.f,0.f,0.f,0.f};

  for (int kc = 0; kc < 256; kc += 32) {
    const float* asrc = sf + ((size_t)(row0+rl))*256 + kc + hf*16;
    __half* adst = As + rl*40 + hf*16;
#pragma unroll
    for (int i=0;i<4;i++){
      float4 v = ((const float4*)asrc)[i];
      __half2 h01 = __floats2half2_rn(v.x, v.y);
      __half2 h23 = __floats2half2_rn(v.z, v.w);
      uint2 u; u.x = *(const unsigned*)&h01; u.y = *(const unsigned*)&h23;
      *(uint2*)(adst + i*4) = u;
    }
    const __half* bsrc = wkT + (size_t)(col0+rl)*256 + kc + hf*16;
    __half* bdst = Bs + rl*40 + hf*16;
    *(uint4*)bdst       = *(const uint4*)bsrc;
    *(uint4*)(bdst + 8) = *(const uint4*)(bsrc + 8);
    __syncthreads();

    half8 af[4], bf[4];
#pragma unroll
    for (int tm=0;tm<4;tm++) af[tm] = *(const half8*)(As + (wm*64 + tm*16 + mr)*40 + qd*8);
#pragma unroll
    for (int tn=0;tn<4;tn++) bf[tn] = *(const half8*)(Bs + (wn*64 + tn*16 + mr)*40 + qd*8);
#pragma unroll
    for (int tm=0;tm<4;tm++)
#pragma unroll
      for (int tn=0;tn<4;tn++)
        acc[tm][tn] = __builtin_amdgcn_mfma_f32_16x16x32_f16(af[tm], bf[tn], acc[tm][tn], 0,0,0);
    __syncthreads();
  }
#pragma unroll
  for (int tm=0;tm<4;tm++)
#pragma unroll
    for (int tn=0;tn<4;tn++){
      int c = col0 + wn*64 + tn*16 + mr;
#pragma unroll
      for (int rg=0; rg<4; rg++){
        int r = row0 + wm*64 + tm*16 + qd*4 + rg;
        float e = ex2(TWO_LOG2E * acc[tm][tn][rg]);       // e^{2*pk}
        Eo[(size_t)r*512 + c] = __float2half(fminf(e, 65000.f));
      }
    }
}

// ---------------- K3: M[net][b][k][e] = sum_d parent[b][d]*bilW[k][d][e]  (fp32) ------
// R7 PMC: 130us, VALUBusy 23%, 0.78 TB/s — latency-bound on the 1-deep W prefetch
// (cover ~250cy << ~900cy stream latency; 2 waves/SIMD -> predicted busy 28% ~= 23%
// measured). Fix: 8-deep rolling prefetch (8 independent dword loads in flight,
// ~2000cy cover). VALU floor 27us, HBM floor ~21us.
__global__ __launch_bounds__(256) void k_M(
    const float* __restrict__ bw_c, const float* __restrict__ bw_p,
    const float* __restrict__ parentT, float* __restrict__ M)
{
  const int net = blockIdx.x >> 8;
  const int k = blockIdx.x & 255;
  const int e = threadIdx.x;
  __shared__ float pl[16384];           // [d][b], 64 KB
#pragma unroll
  for (int r=0;r<16;r++){
    int f4 = r*256 + threadIdx.x;       // 0..4095
    ((float4*)pl)[f4] = ((const float4*)parentT)[f4];
  }
  __syncthreads();

  const float* W = (net ? bw_p : bw_c) + (size_t)k*65536 + e;
  float acc[64];
#pragma unroll
  for (int b=0;b<64;b++) acc[b] = 0.f;

  float wbuf[8];
#pragma unroll
  for (int i=0;i<8;i++) wbuf[i] = W[(size_t)i*256];

  for (int d0=0; d0<256; d0+=8){
    float wnxt[8];
    const int dn = d0 + 8;
    if (dn < 256){
#pragma unroll
      for (int i=0;i<8;i++) wnxt[i] = W[(size_t)(dn+i)*256];
    } else {
#pragma unroll
      for (int i=0;i<8;i++) wnxt[i] = 0.f;
    }
#pragma unroll
    for (int dd=0; dd<8; dd++){
      const float wc = wbuf[dd];
      const float4* pr = (const float4*)(pl + (d0+dd)*64);
#pragma unroll
      for (int c=0;c<16;c++){
        float4 pv = pr[c];
        acc[c*4+0] = fmaf(pv.x, wc, acc[c*4+0]);
        acc[c*4+1] = fmaf(pv.y, wc, acc[c*4+1]);
        acc[c*4+2] = fmaf(pv.z, wc, acc[c*4+2]);
        acc[c*4+3] = fmaf(pv.w, wc, acc[c*4+3]);
      }
    }
#pragma unroll
    for (int i=0;i<8;i++) wbuf[i] = wnxt[i];
  }
  float* Mo = M + ((size_t)net*64*256 + k)*256 + e;
#pragma unroll
  for (int b=0;b<64;b++) Mo[(size_t)b*65536] = acc[b];
}

// ---------------- K4a: gi_all[b][t][j] = x_t[b] . Wih[j] + bih[j] (all t parallel) ----
template<int T>
__global__ __launch_bounds__(256) void k_gi(
    const float* __restrict__ sf, const int* __restrict__ gold,
    const __half* __restrict__ wih, const float* __restrict__ bih,
    float* __restrict__ gi_all)
{
  const int jc = blockIdx.x % 3;
  const int bb = blockIdx.x / 3;
  __shared__ float xs[T-1][256];
  const int* gr = gold + bb*T;
  for (int t=0; t<T-1; t++)
    xs[t][threadIdx.x] = sf[((size_t)bb*L_ + gr[t])*D_ + threadIdx.x];
  __syncthreads();
  const int j = jc*256 + threadIdx.x;
  const __half* wr = wih + (size_t)j*256;
  float acc[T-1];
#pragma unroll
  for (int t=0;t<T-1;t++) acc[t] = 0.f;
  for (int d0=0; d0<256; d0+=8){
    uint4 wv = *(const uint4*)(wr + d0);
    float w[8]; cvt8(wv, w);
#pragma unroll
    for (int t=0;t<T-1;t++){
      const float* xr = &xs[t][d0];
      float4 a = *(const float4*)xr;
      float4 b = *(const float4*)(xr+4);
      acc[t] += w[0]*a.x + w[1]*a.y + w[2]*a.z + w[3]*a.w
              + w[4]*b.x + w[5]*b.y + w[6]*b.z + w[7]*b.w;
    }
  }
  float bias = bih[j];
  float* go = gi_all + ((size_t)bb*32)*768 + j;
#pragma unroll
  for (int t=0;t<T-1;t++) go[(size_t)t*768] = acc[t] + bias;
}

// ---------------- K4b: GRU recurrence, Whh held in VGPRs (128/thread) ------------------
__global__ __launch_bounds__(768, 3) void k_gru(
    const float* __restrict__ query_c, const float* __restrict__ query_p,
    const __half* __restrict__ whhH,
    const float* __restrict__ bhh_c, const float* __restrict__ bhh_p,
    const float* __restrict__ gi_all, float* __restrict__ sibT)
{
  const int net = blockIdx.x >> 6, bb = blockIdx.x & 63;
  const int T = net ? TP : TC;
  const int j = threadIdx.x;
  __shared__ float hs[256];
  __shared__ __half hsh[256];
  __shared__ float gh[768];
  const __half* wr = whhH + (size_t)net*196608 + (size_t)j*256;
  const float bias = (net ? bhh_p : bhh_c)[j];
  const float* gir = gi_all + (size_t)(net*64+bb)*32*768;
  float* sib = sibT + (size_t)(net*64+bb)*256*32;
  const float* query = net ? query_p : query_c;

  uint4 wreg[32];
#pragma unroll
  for (int i=0;i<32;i++) wreg[i] = ((const uint4*)wr)[i];

  if (j < 256){ float h0 = query[j]; hs[j]=h0; hsh[j]=__float2half(h0); sib[j*32]=h0; }
  __syncthreads();
  for (int t=0; t<T-1; t++){
    float a0 = bias, a1 = 0.f, a2 = 0.f, a3 = 0.f;
#pragma unroll
    for (int i=0;i<32;i+=4){
      uint4 hv0 = ((const uint4*)hsh)[i+0];
      uint4 hv1 = ((const uint4*)hsh)[i+1];
      uint4 hv2 = ((const uint4*)hsh)[i+2];
      uint4 hv3 = ((const uint4*)hsh)[i+3];
      const f16x2* wp0 = (const f16x2*)&wreg[i+0]; const f16x2* hp0 = (const f16x2*)&hv0;
      const f16x2* wp1 = (const f16x2*)&wreg[i+1]; const f16x2* hp1 = (const f16x2*)&hv1;
      const f16x2* wp2 = (const f16x2*)&wreg[i+2]; const f16x2* hp2 = (const f16x2*)&hv2;
      const f16x2* wp3 = (const f16x2*)&wreg[i+3]; const f16x2* hp3 = (const f16x2*)&hv3;
#pragma unroll
      for (int i2=0;i2<4;i2++){
        a0 = fdot2_(wp0[i2], hp0[i2], a0);
        a1 = fdot2_(wp1[i2], hp1[i2], a1);
        a2 = fdot2_(wp2[i2], hp2[i2], a2);
        a3 = fdot2_(wp3[i2], hp3[i2], a3);
      }
    }
    gh[j] = (a0 + a1) + (a2 + a3);
    __syncthreads();
    if (j < 256){
      const float* gi = gir + (size_t)t*768;
      float r = sigm(gi[j] + gh[j]);
      float z = sigm(gi[256+j] + gh[256+j]);
      float n = tanh_(gi[512+j] + r*gh[512+j]);
      float hn = (1.f - z)*n + z*hs[j];
      hs[j] = hn; hsh[j] = __float2half(hn);
      sib[j*32 + t + 1] = hn;
    }
    __syncthreads();
  }
}

// ---------------- K5: fused q -> qq -> Q=exp(2*qq), per (net,b,tchunk of 8) -----------
// Q clamped at 3e4 so the fused quad products stay in fp32 range.
__global__ __launch_bounds__(256) void k_qt(
    const float* __restrict__ M, const float* __restrict__ sibT,
    const float* __restrict__ bb_c, const float* __restrict__ bb_p,
    const float* __restrict__ wq_c, const float* __restrict__ wq_p,
    const float* __restrict__ ab_c, const float* __restrict__ ab_p,
    float* __restrict__ Qo)
{
  const int bb = blockIdx.x;
  const int y = blockIdx.y;
  const int net = (y >= 2) ? 1 : 0;
  const int t0 = net ? (y-2)*8 : y*8;
  const int tid = threadIdx.x;
  __shared__ float qs[256][8];
  __shared__ float slds[256][8];

  {
    const float* sr = sibT + ((size_t)(net*64+bb))*256*32 + t0;
#pragma unroll
    for (int r=0;r<2;r++){
      int f4 = r*256 + tid;              // 0..511
      int e = f4 >> 1, hh = f4 & 1;
      *(float4*)&slds[e][hh*4] = *(const float4*)(sr + (size_t)e*32 + hh*4);
    }
  }
  __syncthreads();

  const float* Mr = M + (((size_t)(net*64+bb))*256 + tid)*256;
  float accq[8];
  const float b0 = (net ? bb_p : bb_c)[tid];
#pragma unroll
  for (int t=0;t<8;t++) accq[t] = b0;
  for (int e0=0; e0<256; e0+=4){
    float4 m4 = *(const float4*)(Mr + e0);
#pragma unroll
    for (int ee=0; ee<4; ee++){
      float4 sa = *(const float4*)&slds[e0+ee][0];
      float4 sb = *(const float4*)&slds[e0+ee][4];
      float mv = ((const float*)&m4)[ee];
      accq[0] = fmaf(mv, sa.x, accq[0]); accq[1] = fmaf(mv, sa.y, accq[1]);
      accq[2] = fmaf(mv, sa.z, accq[2]); accq[3] = fmaf(mv, sa.w, accq[3]);
      accq[4] = fmaf(mv, sb.x, accq[4]); accq[5] = fmaf(mv, sb.y, accq[5]);
      accq[6] = fmaf(mv, sb.z, accq[6]); accq[7] = fmaf(mv, sb.w, accq[7]);
    }
  }
#pragma unroll
  for (int t=0;t<8;t++) qs[tid][t] = accq[t];
  __syncthreads();

  const float* wq = (net ? wq_p : wq_c) + tid;
  float acc2[8];
  const float a0 = (net ? ab_p : ab_c)[tid];
#pragma unroll
  for (int t=0;t<8;t++) acc2[t] = a0;
  for (int k=0; k<256; k++){
    float w = wq[(size_t)k*256];
#pragma unroll
    for (int t=0;t<8;t++) acc2[t] = fmaf(qs[k][t], w, acc2[t]);
  }
  float* qo = Qo + (((size_t)(net*64+bb))*256 + tid)*32 + t0;
#pragma unroll
  for (int t=0;t<8;t++) qo[t] = fminf(ex2(TWO_LOG2E * acc2[t]), 3.0e4f);
}

// ---------------- K6: fused scores + exp + partial softmax sums ------------------------
// Single dispatch (R7 lesson: 3-way split cost +59us in dispatch tails). 1D grid 1536.
// id<512: claim (bb,lc), t0=0. id>=512: prem pairs — members m=0 (t0=0) and m=1 (t0=16)
// of pair p sit 8 ids apart => same XCD, co-resident => second member L2-hits the same
// 131 KB of prem-E. Proven R3/R6 inner loop (56 VGPR).
__global__ __launch_bounds__(256) void k_fused(
    const __half* __restrict__ E, const float* __restrict__ Q,
    const float* __restrict__ av_c, const float* __restrict__ av_p,
    const int* __restrict__ mask,
    const int* __restrict__ gold_c, const int* __restrict__ gold_p,
    float* __restrict__ partials, float* __restrict__ gold_e)
{
  const int id = blockIdx.x;
  int bb, lc, t0, net, nc;
  if (id < 512){
    net = 0; nc = 0; t0 = 0; lc = id >> 6; bb = id & 63;
  } else {
    int rid = id - 512;                       // 0..1023
    int m = (rid >> 3) & 1;                   // pair member
    int p = ((rid >> 4) << 3) | (rid & 7);    // pair index 0..511
    net = 1; t0 = m*16; nc = 1 + m; lc = p >> 6; bb = p & 63;
  }
  const int l  = lc*256 + threadIdx.x;
  const __half* pr = E + ((size_t)bb*L_ + l)*512 + net*256;
  const float* qr = Q + ((size_t)(net*64+bb))*256*32 + t0;      // uniform -> s_load
  const float* av = net ? av_p : av_c;

  float acc[16];
#pragma unroll
  for (int t=0;t<16;t++) acc[t] = 0.f;

  for (int d0=0; d0<256; d0+=8){
    uint4 pv = *(const uint4*)(pr + d0);
    float x[8]; cvt8(pv, x);
#pragma unroll
    for (int h=0; h<2; h++){                         // two d-quads per 8 E values
      const int d = d0 + h*4;
      const float v0 = av[d+0], v1 = av[d+1], v2 = av[d+2], v3 = av[d+3];
      const float xa = x[h*4+0], xb = x[h*4+1], xc = x[h*4+2], xd = x[h*4+3];
      const float* q0p = qr + (size_t)(d+0)*32;
      const float* q1p = qr + (size_t)(d+1)*32;
      const float* q2p = qr + (size_t)(d+2)*32;
      const float* q3p = qr + (size_t)(d+3)*32;
#pragma unroll
      for (int tc=0; tc<16; tc+=4){
        float4 qa  = *(const float4*)(q0p + tc);
        float4 qb  = *(const float4*)(q1p + tc);
        float4 qc  = *(const float4*)(q2p + tc);
        float4 qd4 = *(const float4*)(q3p + tc);
        const float qas[4] = {qa.x, qa.y, qa.z, qa.w};
        const float qbs[4] = {qb.x, qb.y, qb.z, qb.w};
        const float qcs[4] = {qc.x, qc.y, qc.z, qc.w};
        const float qds[4] = {qd4.x,qd4.y,qd4.z,qd4.w};
#pragma unroll
        for (int tt=0; tt<4; tt++){
          float ta = fmaf(xa, qas[tt], 1.f);
          float tb = fmaf(xb, qbs[tt], 1.f);
          float tcv= fmaf(xc, qcs[tt], 1.f);
          float td = fmaf(xd, qds[tt], 1.f);
          float t01 = ta*tb, t23 = tcv*td;
          float n01 = fmaf(v0, tb, v1*ta);
          float n23 = fmaf(v2, td, v3*tcv);
          float num = fmaf(n01, t23, n23*t01);
          float den = t01*t23;
          acc[tc+tt] = fmaf(num, rcp_(den), acc[tc+tt]);
        }
      }
    }
  }

  // exp(score) = exp(-2*acc); masked -> 0 contribution (matches exp(NEG) ~ 0)
  const int m_ = mask[bb*L_ + l];
  float ex[16];
#pragma unroll
  for (int t=0;t<16;t++) ex[t] = m_ ? ex2(-TWO_LOG2E * acc[t]) : 0.f;

  // capture gold numerator (exactly one thread per (t) matches across the lc-grid)
  const int* g = net ? (gold_p + bb*TP + t0) : (gold_c + bb*TC);
#pragma unroll
  for (int t=0;t<16;t++)
    if (l == g[t]) gold_e[net*2048 + bb*32 + t0 + t] = ex[t];

  // wave reduction (64 lanes)
#pragma unroll
  for (int off=1; off<64; off<<=1)
#pragma unroll
    for (int t=0;t<16;t++) ex[t] += __shfl_xor(ex[t], off, 64);

  __shared__ float red4[4][16];
  const int lane = threadIdx.x & 63, wave = threadIdx.x >> 6;
  if (lane == 0)
#pragma unroll
    for (int t=0;t<16;t++) red4[wave][t] = ex[t];
  __syncthreads();
  if (threadIdx.x < 16){
    float s = red4[0][threadIdx.x] + red4[1][threadIdx.x]
            + red4[2][threadIdx.x] + red4[3][threadIdx.x];
    partials[(((size_t)nc*64 + bb)*8 + lc)*16 + threadIdx.x] = s;
  }
}

// ---------------- K7: finalize -> out = gold_e / sum(partials) -------------------------
__global__ __launch_bounds__(256) void k_fin(
    const float* __restrict__ partials, const float* __restrict__ gold_e,
    float* __restrict__ out)
{
  int id = blockIdx.x*256 + threadIdx.x;
  if (id >= 3072) return;
  int net, bb, t, nc, tt;
  if (id < 1024){ net=0; bb=id>>4; t=id&15; nc=0; tt=t; }
  else { int i=id-1024; net=1; bb=i>>5; t=i&31; nc=1+(t>>4); tt=t&15; }
  const float* pr = partials + (((size_t)nc*64 + bb)*8)*16 + tt;
  float s = 0.f;
#pragma unroll
  for (int lcx=0; lcx<8; lcx++) s += pr[lcx*16];
  out[net ? (1024 + bb*TP + t) : (bb*TC + t)] = gold_e[net*2048 + bb*32 + t] / s;
}

extern "C" void kernel_launch(void* const* d_in, const int* in_sizes, int n_in,
                              void* d_out, int out_size, void* d_ws, size_t ws_size,
                              hipStream_t stream)
{
  const float* sf      = (const float*)d_in[0];
  const int*   mask    = (const int*)d_in[1];
  const int*   gold_c  = (const int*)d_in[2];
  const int*   gold_p  = (const int*)d_in[3];
  const float* query_c = (const float*)d_in[4];
  const float* query_p = (const float*)d_in[5];
  const float* c_bw  = (const float*)d_in[6];
  const float* c_bb  = (const float*)d_in[7];
  const float* c_wq  = (const float*)d_in[8];
  const float* c_wk  = (const float*)d_in[9];
  const float* c_ab  = (const float*)d_in[10];
  const float* c_av  = (const float*)d_in[11];
  const float* c_wih = (const float*)d_in[12];
  const float* c_whh = (const float*)d_in[13];
  const float* c_bih = (const float*)d_in[14];
  const float* c_bhh = (const float*)d_in[15];
  const float* p_bw  = (const float*)d_in[16];
  const float* p_bb  = (const float*)d_in[17];
  const float* p_wq  = (const float*)d_in[18];
  const float* p_wk  = (const float*)d_in[19];
  const float* p_ab  = (const float*)d_in[20];
  const float* p_av  = (const float*)d_in[21];
  const float* p_wih = (const float*)d_in[22];
  const float* p_whh = (const float*)d_in[23];
  const float* p_bih = (const float*)d_in[24];
  const float* p_bhh = (const float*)d_in[25];
  float* out = (float*)d_out;

  char* w = (char*)d_ws;
  size_t o = 0;
  auto take = [&](size_t bytes){ char* p = w + o; o += (bytes + 255) & ~(size_t)255; return p; };
  __half* E      = (__half*)take((size_t)131072*512*2);       // 134.2 MB  e^{2 pk}
  float*  M      = (float*) take((size_t)2*64*256*256*4);     //  33.6 MB
  float*  Q      = (float*) take((size_t)2*64*256*32*4);      //   4.2 MB  e^{2 qq} (clamped)
  float*  sibT   = (float*) take((size_t)2*64*256*32*4);      //   4.2 MB
  float*  gi_all = (float*) take((size_t)2*64*32*768*4);      //  25.2 MB
  float*  partials=(float*) take((size_t)3*64*8*16*4);        // 196 KB
  float*  gold_e = (float*) take((size_t)2*64*32*4);          //  16 KB
  __half* wkT    = (__half*)take((size_t)512*256*2);
  __half* wihH   = (__half*)take((size_t)2*768*256*2);
  __half* whhH   = (__half*)take((size_t)2*768*256*2);
  float*  parentT= (float*) take((size_t)256*64*4);
  (void)ws_size; (void)in_sizes; (void)n_in; (void)out_size;

  // Order: everything that would pollute L3 runs BEFORE k_gemm, so E (written by
  // k_gemm) is still L3-resident when k_fused reads it.
  k_prep<<<3648, 256, 0, stream>>>(sf, c_wk, p_wk, c_wih, p_wih, c_whh, p_whh,
                                   wkT, wihH, whhH, parentT);
  k_M<<<512, 256, 0, stream>>>(c_bw, p_bw, parentT, M);
  k_gi<TC><<<192, 256, 0, stream>>>(sf, gold_c, wihH,          c_bih, gi_all);
  k_gi<TP><<<192, 256, 0, stream>>>(sf, gold_p, wihH + 196608, p_bih, gi_all + (size_t)64*32*768);
  k_gru<<<128, 768, 0, stream>>>(query_c, query_p, whhH, c_bhh, p_bhh, gi_all, sibT);
  k_qt<<<dim3(64,6), 256, 0, stream>>>(M, sibT, c_bb, p_bb, c_wq, p_wq, c_ab, p_ab, Q);
  k_gemm<<<4096, 256, 0, stream>>>(sf, wkT, E);
  k_fused<<<1536, 256, 0, stream>>>(E, Q, c_av, p_av, mask, gold_c, gold_p,
                                    partials, gold_e);
  k_fin<<<12, 256, 0, stream>>>(partials, gold_e, out);
}